// Round 4
// baseline (230.584 us; speedup 1.0000x reference)
//
#include <hip/hip_runtime.h>
#include <stdint.h>

// LeNet5-XNOR fused pipeline, round 17 (resubmit — infra failure last round).
// vs round 16 (prepsum / reduce / mean / conv2lin byte-identical):
//  - conv1_mfma: 4 waves per image (1 image per 256-thr block, grid 8192).
//    Row-pairs split 4/4/3/3 across waves — halves the per-wave serial
//    dependency chain again (round-14's 1->2 wave split was the proven
//    lever; conv1 is dependency-bound: 6-deep dependent MFMA chain per
//    row-pair, MFMA/VALU floors ~21 us vs ~115 us observed). Staging is
//    1 float4/thread; B-fragment build replicated per wave (one-time,
//    ~190 inst). LDS drops to one 1032-word image buffer.

#define NIMG 8192

typedef __attribute__((ext_vector_type(8))) _Float16 f16x8;
typedef __attribute__((ext_vector_type(16))) float f32x16;
typedef __attribute__((ext_vector_type(4))) int i32x4;
typedef __attribute__((ext_vector_type(16))) int i32x16;

// ---------------- workspace layout ----------------
// 0       : 20 f32     mean
// 5632    : 500 f32    alpha
// 7680    : 500*20 u64 lwp
// 87808   : 512*1024 f32 partial (ends 2184960)
// 2184960 : 8192*196 u32 b1p (ends 8607488)
// 8607488 : 16*1024 f32 partial2 (ends 8673024)
// 8673024 : 25*2*64 i32x4 Bg (conv2 weight frags, 51200 B, ends 8724224)

__global__ __launch_bounds__(256) void prepsum_k(const float* __restrict__ lw,
                                                 const float* __restrict__ w2,
                                                 const float* __restrict__ x,
                                                 unsigned long long* __restrict__ lwp,
                                                 float* __restrict__ alpha,
                                                 i32x4* __restrict__ bg,
                                                 float* __restrict__ partial) {
  int b = blockIdx.x, tid = threadIdx.x;
  if (b < 125) {
    int wave = tid >> 6, lane = tid & 63;
    int j = b * 4 + wave;
    float pa = 0.f;
    for (int k = lane; k < 1250; k += 64) pa += fabsf(lw[j * 1250 + k]);
    for (int o = 32; o > 0; o >>= 1) pa += __shfl_down(pa, o, 64);
    if (lane == 0) alpha[j] = pa / 1250.0f;
    if (lane < 20) {
      unsigned long long m = 0;
      int base = j * 1250 + lane * 64;
      int lim = 1250 - lane * 64; if (lim > 64) lim = 64;
      for (int bb = 0; bb < lim; ++bb)
        if (lw[base + bb] > 0.f) m |= (1ull << bb);
      lwp[j * 20 + lane] = m;
    }
  } else if (b < 138) {
    // conv2 weight fragments in MFMA B layout:
    // Bg[(t*2+nt)*64 + l] = 16 bytes, byte j is k = 16*(l>>5)+j,
    // col oc = nt*32 + (l&31); sign(w2) for k<20 && oc<50 else 0.
    int idx = (b - 125) * 256 + tid;
    if (idx < 3200) {
      int t = idx >> 7;
      int rem = idx & 127;
      int l = rem & 63;
      int nt = rem >> 6;
      int oc = nt * 32 + (l & 31);
      int hi = l >> 5;
      i32x4 o4;
#pragma unroll
      for (int wi = 0; wi < 4; ++wi) {
        int word = 0;
#pragma unroll
        for (int bb = 0; bb < 4; ++bb) {
          int k = hi * 16 + wi * 4 + bb;
          int v = 0;
          if (k < 20 && oc < 50)
            v = (w2[(oc * 20 + k) * 25 + t] > 0.f) ? 1 : -1;
          word |= (v & 0xff) << (8 * bb);
        }
        o4[wi] = word;
      }
      bg[idx] = o4;
    }
  } else {
    int sb = b - 138;
    const float4* xv = (const float4*)x + (size_t)sb * 16 * 256;
    float ax = 0.f, ay = 0.f, az = 0.f, aw = 0.f;
    for (int nn = 0; nn < 16; ++nn) {
      float4 v = xv[nn * 256 + tid];
      ax += v.x; ay += v.y; az += v.z; aw += v.w;
    }
    float4 r; r.x = ax; r.y = ay; r.z = az; r.w = aw;
    ((float4*)(partial + (size_t)sb * 1024))[tid] = r;
  }
}

__global__ __launch_bounds__(256) void reduce_k(const float* __restrict__ partial,
                                                float* __restrict__ partial2) {
  int b = blockIdx.x, tid = threadIdx.x;
  int e = (b & 3) * 256 + tid;
  int p0 = (b >> 2) * 32;
  float s = 0.f;
#pragma unroll
  for (int p = 0; p < 32; ++p) s += partial[(size_t)(p0 + p) * 1024 + e];
  partial2[(size_t)(b >> 2) * 1024 + e] = s;
}

__global__ __launch_bounds__(256) void mean_k(const float* __restrict__ partial2,
                                              const float* __restrict__ w1,
                                              float* __restrict__ mean) {
  __shared__ float Tsh[1024];
  __shared__ double U8[25][8];
  __shared__ double U[25];
  int t = threadIdx.x;
  for (int e = t; e < 1024; e += 256) {
    double s = 0.0;
#pragma unroll
    for (int b = 0; b < 16; ++b) s += (double)partial2[b * 1024 + e];
    Tsh[e] = (float)s;
  }
  __syncthreads();
  if (t < 200) {
    int tap = t >> 3, part = t & 7;
    int ky = tap / 5, kx = tap % 5;
    double s = 0.0;
    for (int p = part * 98; p < part * 98 + 98; ++p) {
      int py = p / 28, px = p % 28;
      s += (double)Tsh[(py + ky) * 32 + px + kx];
    }
    U8[tap][part] = s;
  }
  __syncthreads();
  if (t < 25) {
    double s = 0.0;
    for (int i = 0; i < 8; ++i) s += U8[t][i];
    U[t] = s;
  }
  __syncthreads();
  if (t < 20) {
    double s = 0.0;
    for (int q = 0; q < 25; ++q) s += (double)w1[t * 25 + q] * U[q];
    mean[t] = (float)(s / (8192.0 * 784.0));
  }
}

__device__ inline uint32_t pack_f16_pair(float fv) {
  _Float16 h = (_Float16)fv;
  float rem = fv - (float)h;
  _Float16 l = (_Float16)(rem * 4096.0f);
  uint32_t hb = (uint32_t)__builtin_bit_cast(unsigned short, h);
  uint32_t lb = (uint32_t)__builtin_bit_cast(unsigned short, l);
  return (hb << 16) | lb;
}

// conv1 via MFMA (fp16 2-limb, single 4096-scaled acc chain).
// Block = 256 thr = 4 waves = 1 image; row-pairs split 4/4/3/3.
__global__ __launch_bounds__(256, 6) void conv1_mfma_k(const float* __restrict__ x,
                                                       const float* __restrict__ w1,
                                                       const float* __restrict__ mean,
                                                       uint32_t* __restrict__ b1p) {
  __shared__ uint32_t xs[1032];
  int tid = threadIdx.x;
  int wave = tid >> 6, lane = tid & 63;
  int n = blockIdx.x;

  // ---- stage image (4 waves cooperate, 1 float4/thread) ----
  const float4* xin = (const float4*)(x + (size_t)n * 1024);
  {
    float4 v = xin[tid];
    float fv[4] = {v.x, v.y, v.z, v.w};
#pragma unroll
    for (int e = 0; e < 4; ++e)
      xs[4 * tid + e] = pack_f16_pair(fv[e]);
  }
  if (tid < 8) xs[1024 + tid] = 0;  // pad slots

  // ---- B fragments: Bh (hi), Bhs (hi*4096 exact), Bl (lo*4096) ----
  int bc = lane & 31;
  int khsel = lane >> 5;
  f16x8 Bh[2], Bhs[2], Bl[2];
  const int t1tab[8] = {8, 9, 18, 19, 20, 21, 22, 23};
  const _Float16 SC = (_Float16)4096.0f;
#pragma unroll
  for (int j = 0; j < 8; ++j) {
    int t0 = j + khsel * 10;
    float wv0 = (bc < 20) ? w1[bc * 25 + t0] : 0.f;
    uint32_t p0 = pack_f16_pair(wv0);
    _Float16 h0 = __builtin_bit_cast(_Float16, (unsigned short)(p0 >> 16));
    Bh[0][j] = h0;
    Bhs[0][j] = h0 * SC;
    Bl[0][j] = __builtin_bit_cast(_Float16, (unsigned short)(p0 & 0xffffu));
    float wv1 = 0.f;
    if (bc < 20) {
      if (khsel == 0) wv1 = w1[bc * 25 + t1tab[j]];
      else if (j == 4) wv1 = w1[bc * 25 + 24];
    }
    uint32_t p1 = pack_f16_pair(wv1);
    _Float16 h1 = __builtin_bit_cast(_Float16, (unsigned short)(p1 >> 16));
    Bh[1][j] = h1;
    Bhs[1][j] = h1 * SC;
    Bl[1][j] = __builtin_bit_cast(_Float16, (unsigned short)(p1 & 0xffffu));
  }
  float mv = (bc < 20) ? mean[bc] * 4096.0f : 3.0e38f;

  int m = lane & 31;
  int d0 = m + khsel * 64;
  int d1 = m + khsel * 4;

  __syncthreads();

  int pp0 = (wave < 2) ? wave * 4 : 8 + (wave - 2) * 3;
  int cnt = (wave < 2) ? 4 : 3;
  for (int pp = pp0; pp < pp0 + cnt; ++pp) {
    unsigned long long bacc[16];
#pragma unroll
    for (int r = 0; r < 16; ++r) bacc[r] = 0ull;
#pragma unroll
    for (int py2 = 0; py2 < 2; ++py2) {
      int pybase = (2 * pp + py2) * 32;
      const uint32_t* b0 = xs + pybase + d0;
      const uint32_t* b1 = xs + pybase + d1;
      uint32_t raw[16];
      raw[0] = b0[0];   raw[1] = b0[1];   raw[2] = b0[2];   raw[3] = b0[3];
      raw[4] = b0[4];   raw[5] = b0[32];  raw[6] = b0[33];  raw[7] = b0[34];
      raw[8] = b1[35];  raw[9] = b1[36];  raw[10] = b1[99]; raw[11] = b1[100];
      raw[12] = b1[128]; raw[13] = b1[129]; raw[14] = b1[130]; raw[15] = b1[131];
      f16x8 Ah[2], Al[2];
#pragma unroll
      for (int kh = 0; kh < 2; ++kh) {
        uint32_t hw[4], lw2[4];
#pragma unroll
        for (int jj = 0; jj < 4; ++jj) {
          uint32_t v0 = raw[kh * 8 + 2 * jj], v1 = raw[kh * 8 + 2 * jj + 1];
          hw[jj] = __builtin_amdgcn_perm(v1, v0, 0x07060302u);
          lw2[jj] = __builtin_amdgcn_perm(v1, v0, 0x05040100u);
        }
        struct U4 { uint32_t a, b, c, d; };
        U4 hv4 = {hw[0], hw[1], hw[2], hw[3]};
        U4 lv4 = {lw2[0], lw2[1], lw2[2], lw2[3]};
        Ah[kh] = __builtin_bit_cast(f16x8, hv4);
        Al[kh] = __builtin_bit_cast(f16x8, lv4);
      }
      f32x16 acc;
#pragma unroll
      for (int i = 0; i < 16; ++i) acc[i] = 0.f;
      acc = __builtin_amdgcn_mfma_f32_32x32x16_f16(Ah[0], Bhs[0], acc, 0, 0, 0);
      acc = __builtin_amdgcn_mfma_f32_32x32x16_f16(Ah[1], Bhs[1], acc, 0, 0, 0);
      acc = __builtin_amdgcn_mfma_f32_32x32x16_f16(Ah[0], Bl[0], acc, 0, 0, 0);
      acc = __builtin_amdgcn_mfma_f32_32x32x16_f16(Ah[1], Bl[1], acc, 0, 0, 0);
      acc = __builtin_amdgcn_mfma_f32_32x32x16_f16(Al[0], Bh[0], acc, 0, 0, 0);
      acc = __builtin_amdgcn_mfma_f32_32x32x16_f16(Al[1], Bh[1], acc, 0, 0, 0);
      // C/D: channel = lane&31, px = (r&3) + 8*(r>>2) + 4*(lane>>5)
#pragma unroll
      for (int r = 0; r < 16; ++r)
        bacc[r] |= __ballot(acc[r] > mv);
    }
    uint32_t pm = 0;
#pragma unroll
    for (int pc = 0; pc < 14; ++pc) {
      int px0 = 2 * pc;
      int r0 = (px0 & 3) + 4 * (px0 >> 3);
      int h0 = (px0 >> 2) & 1;
      unsigned long long mm = bacc[r0] | bacc[r0 + 1];
      uint32_t val = (uint32_t)(mm >> (32 * h0));
      if (lane == pc) pm = val;
    }
    if (lane < 14) b1p[(size_t)n * 196 + pp * 14 + lane] = pm;
  }
}

// Fused conv2(i8 MFMA, reg-built A)+pool/sign+linear+fc.
__global__ __launch_bounds__(512, 6) void conv2lin_k(const uint32_t* __restrict__ b1p,
                                                     const i32x4* __restrict__ bg,
                                                     const unsigned long long* __restrict__ lwp,
                                                     const float* __restrict__ alpha,
                                                     const float* __restrict__ fcw,
                                                     const float* __restrict__ fcb,
                                                     float* __restrict__ out) {
  __shared__ uint32_t b1sh[1568];                             // 6272 B
  __shared__ __attribute__((aligned(16))) char uni[8][2048];  // 16384 B
  int tid = threadIdx.x;
  int wave = tid >> 6, lane = tid & 63;
  int n0 = blockIdx.x * 8;

  // ---- stage raw b1p words (bit-planes) ----
#pragma unroll
  for (int r = 0; r < 4; ++r) {
    int idx = r * 512 + tid;
    if (idx < 1568) b1sh[idx] = b1p[(size_t)n0 * 196 + idx];
  }
  __syncthreads();

  // ---- conv2: tap-decomposed i8 GEMM, M = 8img*25quads*4 = 25 tiles ----
  // A fragment rebuilt in registers per tap: 16 bits of one b1p word
  // spread to 16 i8 bytes (bits 20..31 are 0 => pad channels 0).
  {
    int m = lane & 31, hi = lane >> 5;
    int shbase = hi * 16;
    for (int mt = wave; mt < 25; mt += 8) {
      int qg = mt * 8 + (m >> 2);
      int img = (qg * 41) >> 10;       // /25 for qg<200
      int quad = qg - img * 25;
      int Y = (quad * 13) >> 6;        // /5 for quad<25
      int X = quad - Y * 5;
      int px = (2 * Y + ((m >> 1) & 1)) * 14 + 2 * X + (m & 1);
      const uint32_t* arow = b1sh + img * 196 + px;
      const i32x4* bgl = bg + lane;
      i32x16 acc0, acc1;
#pragma unroll
      for (int i = 0; i < 16; ++i) { acc0[i] = 0; acc1[i] = 0; }
#pragma unroll 1
      for (int ky = 0; ky < 5; ++ky) {
        const uint32_t* ar2 = arow + ky * 14;
        const i32x4* bg2 = bgl + ky * 5 * 128;
#pragma unroll
        for (int kx = 0; kx < 5; ++kx) {
          uint32_t w = ar2[kx];
          i32x4 av;
#pragma unroll
          for (int wi = 0; wi < 4; ++wi)
            av[wi] = (int)((((w >> (shbase + 4 * wi)) & 0xFu) * 0x00204081u) & 0x01010101u);
          i32x4 bv0 = bg2[kx * 128];
          i32x4 bv1 = bg2[kx * 128 + 64];
          acc0 = __builtin_amdgcn_mfma_i32_32x32x32_i8(av, bv0, acc0, 0, 0, 0);
          acc1 = __builtin_amdgcn_mfma_i32_32x32x32_i8(av, bv1, acc1, 0, 0, 0);
        }
      }
      // readout: col oc = nt*32 + (lane&31); rows 4*(2g+hi)+{0..3} = regs 4g..4g+3
      int oc0 = m, oc1 = 32 + m;
#pragma unroll
      for (int g = 0; g < 4; ++g) {
        int qloc = 2 * g + hi;
        int qg2 = mt * 8 + qloc;
        int img2 = (qg2 * 41) >> 10;
        int quad2 = qg2 - img2 * 25;
        {
          int a0 = acc0[4 * g], a1 = acc0[4 * g + 1], a2 = acc0[4 * g + 2], a3 = acc0[4 * g + 3];
          int c0 = a0 > a1 ? a0 : a1, c1 = a2 > a3 ? a2 : a3;
          int best = c0 > c1 ? c0 : c1;
          uni[img2][oc0 * 25 + quad2] = (char)((best > 0) - (best < 0));
        }
        if (oc1 < 50) {
          int a0 = acc1[4 * g], a1 = acc1[4 * g + 1], a2 = acc1[4 * g + 2], a3 = acc1[4 * g + 3];
          int c0 = a0 > a1 ? a0 : a1, c1 = a2 > a3 ? a2 : a3;
          int best = c0 > c1 ? c0 : c1;
          uni[img2][oc1 * 25 + quad2] = (char)((best > 0) - (best < 0));
        }
      }
    }
  }
  __syncthreads();

  // ---- linear + fc (per-wave own image), unchanged ----
  int n = n0 + wave;
  signed char* s2w = (signed char*)uni[wave];
  float* hshw = (float*)uni[wave];
  if (lane < 30) s2w[1250 + lane] = 0;

  unsigned long long Pm[20], Nm[20];
  int cp = 0, cn = 0;
#pragma unroll
  for (int k = 0; k < 20; ++k) {
    signed char v = s2w[k * 64 + lane];
    unsigned long long P = __ballot(v > 0);
    unsigned long long N = __ballot(v < 0);
    Pm[k] = P; Nm[k] = N;
    cp += __popcll(P); cn += __popcll(N);
  }

#pragma unroll
  for (int rd = 0; rd < 8; ++rd) {
    int j = rd * 64 + lane;
    float y = 0.f;
    if (j < 500) {
      const ulonglong2* W2 = (const ulonglong2*)(lwp + (size_t)j * 20);
      int a = 0, b = 0;
#pragma unroll
      for (int i = 0; i < 10; ++i) {
        ulonglong2 w2v = W2[i];
        a += __popcll(w2v.x & Pm[2 * i]) + __popcll(w2v.y & Pm[2 * i + 1]);
        b += __popcll(w2v.x & Nm[2 * i]) + __popcll(w2v.y & Nm[2 * i + 1]);
      }
      int dot = 2 * (a - b) - cp + cn;
      y = alpha[j] * (float)dot;
      y = fminf(1.0f, fmaxf(-1.0f, y));
    }
    hshw[rd * 64 + lane] = y;
  }

  float hv[8];
#pragma unroll
  for (int k = 0; k < 8; ++k) hv[k] = hshw[k * 64 + lane];
#pragma unroll
  for (int o = 0; o < 10; ++o) {
    float pa = 0.f;
#pragma unroll
    for (int k = 0; k < 8; ++k) {
      int j = k * 64 + lane;
      if (j < 500) pa += hv[k] * fcw[o * 500 + j];
    }
    for (int off = 32; off > 0; off >>= 1) pa += __shfl_down(pa, off, 64);
    if (lane == 0) out[(size_t)n * 10 + o] = pa + fcb[o];
  }
}

extern "C" void kernel_launch(void* const* d_in, const int* in_sizes, int n_in,
                              void* d_out, int out_size, void* d_ws, size_t ws_size,
                              hipStream_t stream) {
  const float* x   = (const float*)d_in[0];
  const float* w1  = (const float*)d_in[1];
  const float* w2  = (const float*)d_in[2];
  const float* lw  = (const float*)d_in[3];
  const float* fcw = (const float*)d_in[4];
  const float* fcb = (const float*)d_in[5];
  float* out = (float*)d_out;
  char* ws = (char*)d_ws;

  float*    mean  = (float*)(ws + 0);
  float*    alpha = (float*)(ws + 5632);
  unsigned long long* lwp = (unsigned long long*)(ws + 7680);
  float*    partial = (float*)(ws + 87808);
  uint32_t* b1p   = (uint32_t*)(ws + 2184960);
  float*    partial2 = (float*)(ws + 8607488);
  i32x4*    bg    = (i32x4*)(ws + 8673024);

  prepsum_k<<<650, 256, 0, stream>>>(lw, w2, x, lwp, alpha, bg, partial);
  reduce_k<<<64, 256, 0, stream>>>(partial, partial2);
  mean_k<<<1, 256, 0, stream>>>(partial2, w1, mean);
  conv1_mfma_k<<<8192, 256, 0, stream>>>(x, w1, mean, b1p);
  conv2lin_k<<<1024, 512, 0, stream>>>(b1p, bg, lwp, alpha, fcw, fcb, out);
}

// Round 5
// 227.302 us; speedup vs baseline: 1.0144x; 1.0144x over previous
//
#include <hip/hip_runtime.h>
#include <stdint.h>

// LeNet5-XNOR fused pipeline, round 18.
// vs round 17 (prepsum / reduce / mean / conv1_mfma byte-identical):
//  - conv2lin_k: B fragments (bg, 51.2KB) staged into LDS once per block.
//    Previously every tap of every tile reloaded B from global: 1.28 MB of
//    L2 reads per block (1.3 GB total, ~38us L2-BW floor + 200-500cy
//    latency on the MFMA critical path => MfmaUtil 15%). Now inner loop is
//    ds_read_b32 (A word) + 2x ds_read_b128 (B) + spread + 2 MFMA, all
//    LDS-latency (~120cy, hideable). LDS 23->73.9KB, still 2 blocks/CU
//    (matches measured occupancy). L2 B-traffic cut 25x.

#define NIMG 8192

typedef __attribute__((ext_vector_type(8))) _Float16 f16x8;
typedef __attribute__((ext_vector_type(16))) float f32x16;
typedef __attribute__((ext_vector_type(4))) int i32x4;
typedef __attribute__((ext_vector_type(16))) int i32x16;

// ---------------- workspace layout ----------------
// 0       : 20 f32     mean
// 5632    : 500 f32    alpha
// 7680    : 500*20 u64 lwp
// 87808   : 512*1024 f32 partial (ends 2184960)
// 2184960 : 8192*196 u32 b1p (ends 8607488)
// 8607488 : 16*1024 f32 partial2 (ends 8673024)
// 8673024 : 25*2*64 i32x4 Bg (conv2 weight frags, 51200 B, ends 8724224)

__global__ __launch_bounds__(256) void prepsum_k(const float* __restrict__ lw,
                                                 const float* __restrict__ w2,
                                                 const float* __restrict__ x,
                                                 unsigned long long* __restrict__ lwp,
                                                 float* __restrict__ alpha,
                                                 i32x4* __restrict__ bg,
                                                 float* __restrict__ partial) {
  int b = blockIdx.x, tid = threadIdx.x;
  if (b < 125) {
    int wave = tid >> 6, lane = tid & 63;
    int j = b * 4 + wave;
    float pa = 0.f;
    for (int k = lane; k < 1250; k += 64) pa += fabsf(lw[j * 1250 + k]);
    for (int o = 32; o > 0; o >>= 1) pa += __shfl_down(pa, o, 64);
    if (lane == 0) alpha[j] = pa / 1250.0f;
    if (lane < 20) {
      unsigned long long m = 0;
      int base = j * 1250 + lane * 64;
      int lim = 1250 - lane * 64; if (lim > 64) lim = 64;
      for (int bb = 0; bb < lim; ++bb)
        if (lw[base + bb] > 0.f) m |= (1ull << bb);
      lwp[j * 20 + lane] = m;
    }
  } else if (b < 138) {
    // conv2 weight fragments in MFMA B layout:
    // Bg[(t*2+nt)*64 + l] = 16 bytes, byte j is k = 16*(l>>5)+j,
    // col oc = nt*32 + (l&31); sign(w2) for k<20 && oc<50 else 0.
    int idx = (b - 125) * 256 + tid;
    if (idx < 3200) {
      int t = idx >> 7;
      int rem = idx & 127;
      int l = rem & 63;
      int nt = rem >> 6;
      int oc = nt * 32 + (l & 31);
      int hi = l >> 5;
      i32x4 o4;
#pragma unroll
      for (int wi = 0; wi < 4; ++wi) {
        int word = 0;
#pragma unroll
        for (int bb = 0; bb < 4; ++bb) {
          int k = hi * 16 + wi * 4 + bb;
          int v = 0;
          if (k < 20 && oc < 50)
            v = (w2[(oc * 20 + k) * 25 + t] > 0.f) ? 1 : -1;
          word |= (v & 0xff) << (8 * bb);
        }
        o4[wi] = word;
      }
      bg[idx] = o4;
    }
  } else {
    int sb = b - 138;
    const float4* xv = (const float4*)x + (size_t)sb * 16 * 256;
    float ax = 0.f, ay = 0.f, az = 0.f, aw = 0.f;
    for (int nn = 0; nn < 16; ++nn) {
      float4 v = xv[nn * 256 + tid];
      ax += v.x; ay += v.y; az += v.z; aw += v.w;
    }
    float4 r; r.x = ax; r.y = ay; r.z = az; r.w = aw;
    ((float4*)(partial + (size_t)sb * 1024))[tid] = r;
  }
}

__global__ __launch_bounds__(256) void reduce_k(const float* __restrict__ partial,
                                                float* __restrict__ partial2) {
  int b = blockIdx.x, tid = threadIdx.x;
  int e = (b & 3) * 256 + tid;
  int p0 = (b >> 2) * 32;
  float s = 0.f;
#pragma unroll
  for (int p = 0; p < 32; ++p) s += partial[(size_t)(p0 + p) * 1024 + e];
  partial2[(size_t)(b >> 2) * 1024 + e] = s;
}

__global__ __launch_bounds__(256) void mean_k(const float* __restrict__ partial2,
                                              const float* __restrict__ w1,
                                              float* __restrict__ mean) {
  __shared__ float Tsh[1024];
  __shared__ double U8[25][8];
  __shared__ double U[25];
  int t = threadIdx.x;
  for (int e = t; e < 1024; e += 256) {
    double s = 0.0;
#pragma unroll
    for (int b = 0; b < 16; ++b) s += (double)partial2[b * 1024 + e];
    Tsh[e] = (float)s;
  }
  __syncthreads();
  if (t < 200) {
    int tap = t >> 3, part = t & 7;
    int ky = tap / 5, kx = tap % 5;
    double s = 0.0;
    for (int p = part * 98; p < part * 98 + 98; ++p) {
      int py = p / 28, px = p % 28;
      s += (double)Tsh[(py + ky) * 32 + px + kx];
    }
    U8[tap][part] = s;
  }
  __syncthreads();
  if (t < 25) {
    double s = 0.0;
    for (int i = 0; i < 8; ++i) s += U8[t][i];
    U[t] = s;
  }
  __syncthreads();
  if (t < 20) {
    double s = 0.0;
    for (int q = 0; q < 25; ++q) s += (double)w1[t * 25 + q] * U[q];
    mean[t] = (float)(s / (8192.0 * 784.0));
  }
}

__device__ inline uint32_t pack_f16_pair(float fv) {
  _Float16 h = (_Float16)fv;
  float rem = fv - (float)h;
  _Float16 l = (_Float16)(rem * 4096.0f);
  uint32_t hb = (uint32_t)__builtin_bit_cast(unsigned short, h);
  uint32_t lb = (uint32_t)__builtin_bit_cast(unsigned short, l);
  return (hb << 16) | lb;
}

// conv1 via MFMA (fp16 2-limb, single 4096-scaled acc chain).
// Block = 256 thr = 4 waves = 1 image; row-pairs split 4/4/3/3.
__global__ __launch_bounds__(256, 6) void conv1_mfma_k(const float* __restrict__ x,
                                                       const float* __restrict__ w1,
                                                       const float* __restrict__ mean,
                                                       uint32_t* __restrict__ b1p) {
  __shared__ uint32_t xs[1032];
  int tid = threadIdx.x;
  int wave = tid >> 6, lane = tid & 63;
  int n = blockIdx.x;

  // ---- stage image (4 waves cooperate, 1 float4/thread) ----
  const float4* xin = (const float4*)(x + (size_t)n * 1024);
  {
    float4 v = xin[tid];
    float fv[4] = {v.x, v.y, v.z, v.w};
#pragma unroll
    for (int e = 0; e < 4; ++e)
      xs[4 * tid + e] = pack_f16_pair(fv[e]);
  }
  if (tid < 8) xs[1024 + tid] = 0;  // pad slots

  // ---- B fragments: Bh (hi), Bhs (hi*4096 exact), Bl (lo*4096) ----
  int bc = lane & 31;
  int khsel = lane >> 5;
  f16x8 Bh[2], Bhs[2], Bl[2];
  const int t1tab[8] = {8, 9, 18, 19, 20, 21, 22, 23};
  const _Float16 SC = (_Float16)4096.0f;
#pragma unroll
  for (int j = 0; j < 8; ++j) {
    int t0 = j + khsel * 10;
    float wv0 = (bc < 20) ? w1[bc * 25 + t0] : 0.f;
    uint32_t p0 = pack_f16_pair(wv0);
    _Float16 h0 = __builtin_bit_cast(_Float16, (unsigned short)(p0 >> 16));
    Bh[0][j] = h0;
    Bhs[0][j] = h0 * SC;
    Bl[0][j] = __builtin_bit_cast(_Float16, (unsigned short)(p0 & 0xffffu));
    float wv1 = 0.f;
    if (bc < 20) {
      if (khsel == 0) wv1 = w1[bc * 25 + t1tab[j]];
      else if (j == 4) wv1 = w1[bc * 25 + 24];
    }
    uint32_t p1 = pack_f16_pair(wv1);
    _Float16 h1 = __builtin_bit_cast(_Float16, (unsigned short)(p1 >> 16));
    Bh[1][j] = h1;
    Bhs[1][j] = h1 * SC;
    Bl[1][j] = __builtin_bit_cast(_Float16, (unsigned short)(p1 & 0xffffu));
  }
  float mv = (bc < 20) ? mean[bc] * 4096.0f : 3.0e38f;

  int m = lane & 31;
  int d0 = m + khsel * 64;
  int d1 = m + khsel * 4;

  __syncthreads();

  int pp0 = (wave < 2) ? wave * 4 : 8 + (wave - 2) * 3;
  int cnt = (wave < 2) ? 4 : 3;
  for (int pp = pp0; pp < pp0 + cnt; ++pp) {
    unsigned long long bacc[16];
#pragma unroll
    for (int r = 0; r < 16; ++r) bacc[r] = 0ull;
#pragma unroll
    for (int py2 = 0; py2 < 2; ++py2) {
      int pybase = (2 * pp + py2) * 32;
      const uint32_t* b0 = xs + pybase + d0;
      const uint32_t* b1 = xs + pybase + d1;
      uint32_t raw[16];
      raw[0] = b0[0];   raw[1] = b0[1];   raw[2] = b0[2];   raw[3] = b0[3];
      raw[4] = b0[4];   raw[5] = b0[32];  raw[6] = b0[33];  raw[7] = b0[34];
      raw[8] = b1[35];  raw[9] = b1[36];  raw[10] = b1[99]; raw[11] = b1[100];
      raw[12] = b1[128]; raw[13] = b1[129]; raw[14] = b1[130]; raw[15] = b1[131];
      f16x8 Ah[2], Al[2];
#pragma unroll
      for (int kh = 0; kh < 2; ++kh) {
        uint32_t hw[4], lw2[4];
#pragma unroll
        for (int jj = 0; jj < 4; ++jj) {
          uint32_t v0 = raw[kh * 8 + 2 * jj], v1 = raw[kh * 8 + 2 * jj + 1];
          hw[jj] = __builtin_amdgcn_perm(v1, v0, 0x07060302u);
          lw2[jj] = __builtin_amdgcn_perm(v1, v0, 0x05040100u);
        }
        struct U4 { uint32_t a, b, c, d; };
        U4 hv4 = {hw[0], hw[1], hw[2], hw[3]};
        U4 lv4 = {lw2[0], lw2[1], lw2[2], lw2[3]};
        Ah[kh] = __builtin_bit_cast(f16x8, hv4);
        Al[kh] = __builtin_bit_cast(f16x8, lv4);
      }
      f32x16 acc;
#pragma unroll
      for (int i = 0; i < 16; ++i) acc[i] = 0.f;
      acc = __builtin_amdgcn_mfma_f32_32x32x16_f16(Ah[0], Bhs[0], acc, 0, 0, 0);
      acc = __builtin_amdgcn_mfma_f32_32x32x16_f16(Ah[1], Bhs[1], acc, 0, 0, 0);
      acc = __builtin_amdgcn_mfma_f32_32x32x16_f16(Ah[0], Bl[0], acc, 0, 0, 0);
      acc = __builtin_amdgcn_mfma_f32_32x32x16_f16(Ah[1], Bl[1], acc, 0, 0, 0);
      acc = __builtin_amdgcn_mfma_f32_32x32x16_f16(Al[0], Bh[0], acc, 0, 0, 0);
      acc = __builtin_amdgcn_mfma_f32_32x32x16_f16(Al[1], Bh[1], acc, 0, 0, 0);
      // C/D: channel = lane&31, px = (r&3) + 8*(r>>2) + 4*(lane>>5)
#pragma unroll
      for (int r = 0; r < 16; ++r)
        bacc[r] |= __ballot(acc[r] > mv);
    }
    uint32_t pm = 0;
#pragma unroll
    for (int pc = 0; pc < 14; ++pc) {
      int px0 = 2 * pc;
      int r0 = (px0 & 3) + 4 * (px0 >> 3);
      int h0 = (px0 >> 2) & 1;
      unsigned long long mm = bacc[r0] | bacc[r0 + 1];
      uint32_t val = (uint32_t)(mm >> (32 * h0));
      if (lane == pc) pm = val;
    }
    if (lane < 14) b1p[(size_t)n * 196 + pp * 14 + lane] = pm;
  }
}

// Fused conv2(i8 MFMA, LDS-staged B, reg-built A)+pool/sign+linear+fc.
__global__ __launch_bounds__(512, 4) void conv2lin_k(const uint32_t* __restrict__ b1p,
                                                     const i32x4* __restrict__ bg,
                                                     const unsigned long long* __restrict__ lwp,
                                                     const float* __restrict__ alpha,
                                                     const float* __restrict__ fcw,
                                                     const float* __restrict__ fcb,
                                                     float* __restrict__ out) {
  __shared__ uint32_t b1sh[1568];                             // 6272 B
  __shared__ __attribute__((aligned(16))) i32x4 bglds[3200];  // 51200 B
  __shared__ __attribute__((aligned(16))) char uni[8][2048];  // 16384 B
  int tid = threadIdx.x;
  int wave = tid >> 6, lane = tid & 63;
  int n0 = blockIdx.x * 8;

  // ---- stage B fragments (51.2KB, wave-invariant, L2-broadcast) ----
  for (int i = tid; i < 3200; i += 512) bglds[i] = bg[i];
  // ---- stage raw b1p words (bit-planes) ----
#pragma unroll
  for (int r = 0; r < 4; ++r) {
    int idx = r * 512 + tid;
    if (idx < 1568) b1sh[idx] = b1p[(size_t)n0 * 196 + idx];
  }
  __syncthreads();

  // ---- conv2: tap-decomposed i8 GEMM, M = 8img*25quads*4 = 25 tiles ----
  // A fragment rebuilt in registers per tap: 16 bits of one b1p word
  // spread to 16 i8 bytes (bits 20..31 are 0 => pad channels 0).
  {
    int m = lane & 31, hi = lane >> 5;
    int shbase = hi * 16;
    for (int mt = wave; mt < 25; mt += 8) {
      int qg = mt * 8 + (m >> 2);
      int img = (qg * 41) >> 10;       // /25 for qg<200
      int quad = qg - img * 25;
      int Y = (quad * 13) >> 6;        // /5 for quad<25
      int X = quad - Y * 5;
      int px = (2 * Y + ((m >> 1) & 1)) * 14 + 2 * X + (m & 1);
      const uint32_t* arow = b1sh + img * 196 + px;
      const i32x4* bgl = bglds + lane;
      i32x16 acc0, acc1;
#pragma unroll
      for (int i = 0; i < 16; ++i) { acc0[i] = 0; acc1[i] = 0; }
#pragma unroll 1
      for (int ky = 0; ky < 5; ++ky) {
        const uint32_t* ar2 = arow + ky * 14;
        const i32x4* bg2 = bgl + ky * 5 * 128;
#pragma unroll
        for (int kx = 0; kx < 5; ++kx) {
          uint32_t w = ar2[kx];
          i32x4 av;
#pragma unroll
          for (int wi = 0; wi < 4; ++wi)
            av[wi] = (int)((((w >> (shbase + 4 * wi)) & 0xFu) * 0x00204081u) & 0x01010101u);
          i32x4 bv0 = bg2[kx * 128];
          i32x4 bv1 = bg2[kx * 128 + 64];
          acc0 = __builtin_amdgcn_mfma_i32_32x32x32_i8(av, bv0, acc0, 0, 0, 0);
          acc1 = __builtin_amdgcn_mfma_i32_32x32x32_i8(av, bv1, acc1, 0, 0, 0);
        }
      }
      // readout: col oc = nt*32 + (lane&31); rows 4*(2g+hi)+{0..3} = regs 4g..4g+3
      int oc0 = m, oc1 = 32 + m;
#pragma unroll
      for (int g = 0; g < 4; ++g) {
        int qloc = 2 * g + hi;
        int qg2 = mt * 8 + qloc;
        int img2 = (qg2 * 41) >> 10;
        int quad2 = qg2 - img2 * 25;
        {
          int a0 = acc0[4 * g], a1 = acc0[4 * g + 1], a2 = acc0[4 * g + 2], a3 = acc0[4 * g + 3];
          int c0 = a0 > a1 ? a0 : a1, c1 = a2 > a3 ? a2 : a3;
          int best = c0 > c1 ? c0 : c1;
          uni[img2][oc0 * 25 + quad2] = (char)((best > 0) - (best < 0));
        }
        if (oc1 < 50) {
          int a0 = acc1[4 * g], a1 = acc1[4 * g + 1], a2 = acc1[4 * g + 2], a3 = acc1[4 * g + 3];
          int c0 = a0 > a1 ? a0 : a1, c1 = a2 > a3 ? a2 : a3;
          int best = c0 > c1 ? c0 : c1;
          uni[img2][oc1 * 25 + quad2] = (char)((best > 0) - (best < 0));
        }
      }
    }
  }
  __syncthreads();

  // ---- linear + fc (per-wave own image), unchanged ----
  int n = n0 + wave;
  signed char* s2w = (signed char*)uni[wave];
  float* hshw = (float*)uni[wave];
  if (lane < 30) s2w[1250 + lane] = 0;

  unsigned long long Pm[20], Nm[20];
  int cp = 0, cn = 0;
#pragma unroll
  for (int k = 0; k < 20; ++k) {
    signed char v = s2w[k * 64 + lane];
    unsigned long long P = __ballot(v > 0);
    unsigned long long N = __ballot(v < 0);
    Pm[k] = P; Nm[k] = N;
    cp += __popcll(P); cn += __popcll(N);
  }

#pragma unroll
  for (int rd = 0; rd < 8; ++rd) {
    int j = rd * 64 + lane;
    float y = 0.f;
    if (j < 500) {
      const ulonglong2* W2 = (const ulonglong2*)(lwp + (size_t)j * 20);
      int a = 0, b = 0;
#pragma unroll
      for (int i = 0; i < 10; ++i) {
        ulonglong2 w2v = W2[i];
        a += __popcll(w2v.x & Pm[2 * i]) + __popcll(w2v.y & Pm[2 * i + 1]);
        b += __popcll(w2v.x & Nm[2 * i]) + __popcll(w2v.y & Nm[2 * i + 1]);
      }
      int dot = 2 * (a - b) - cp + cn;
      y = alpha[j] * (float)dot;
      y = fminf(1.0f, fmaxf(-1.0f, y));
    }
    hshw[rd * 64 + lane] = y;
  }

  float hv[8];
#pragma unroll
  for (int k = 0; k < 8; ++k) hv[k] = hshw[k * 64 + lane];
#pragma unroll
  for (int o = 0; o < 10; ++o) {
    float pa = 0.f;
#pragma unroll
    for (int k = 0; k < 8; ++k) {
      int j = k * 64 + lane;
      if (j < 500) pa += hv[k] * fcw[o * 500 + j];
    }
    for (int off = 32; off > 0; off >>= 1) pa += __shfl_down(pa, off, 64);
    if (lane == 0) out[(size_t)n * 10 + o] = pa + fcb[o];
  }
}

extern "C" void kernel_launch(void* const* d_in, const int* in_sizes, int n_in,
                              void* d_out, int out_size, void* d_ws, size_t ws_size,
                              hipStream_t stream) {
  const float* x   = (const float*)d_in[0];
  const float* w1  = (const float*)d_in[1];
  const float* w2  = (const float*)d_in[2];
  const float* lw  = (const float*)d_in[3];
  const float* fcw = (const float*)d_in[4];
  const float* fcb = (const float*)d_in[5];
  float* out = (float*)d_out;
  char* ws = (char*)d_ws;

  float*    mean  = (float*)(ws + 0);
  float*    alpha = (float*)(ws + 5632);
  unsigned long long* lwp = (unsigned long long*)(ws + 7680);
  float*    partial = (float*)(ws + 87808);
  uint32_t* b1p   = (uint32_t*)(ws + 2184960);
  float*    partial2 = (float*)(ws + 8607488);
  i32x4*    bg    = (i32x4*)(ws + 8673024);

  prepsum_k<<<650, 256, 0, stream>>>(lw, w2, x, lwp, alpha, bg, partial);
  reduce_k<<<64, 256, 0, stream>>>(partial, partial2);
  mean_k<<<1, 256, 0, stream>>>(partial2, w1, mean);
  conv1_mfma_k<<<8192, 256, 0, stream>>>(x, w1, mean, b1p);
  conv2lin_k<<<1024, 512, 0, stream>>>(b1p, bg, lwp, alpha, fcw, fcb, out);
}

// Round 6
// 219.422 us; speedup vs baseline: 1.0509x; 1.0359x over previous
//
#include <hip/hip_runtime.h>
#include <stdint.h>

// LeNet5-XNOR fused pipeline, round 19.
// vs round 18 (prepsum / reduce / mean byte-identical):
//  - conv1_mfma_k + conv2lin_k FUSED into conv12_k (512 thr, 8 img/block,
//    grid 1024). Phase 1: wave w = conv1 of image w (stage+pack into
//    wave-private xs8[w], 14 row-pairs, ballots -> b1sh in LDS). One
//    barrier. Phase 2/3: round-16 conv2 (i8 MFMA, reg-built A, global-L2
//    bg) + lin + fc, byte-identical logic.
//    Deletes: conv1 dispatch + launch gap, b1p global write/read (13 MB),
//    b1p->LDS restage, x4-replicated conv1 prologue (B-frags once/image).
//    Cross-phase pipe overlap across the 2 co-resident blocks/CU.
//    LDS 55.7KB (xs 33K + b1sh 6.3K + uni 16K) -> 2 blocks/CU.

#define NIMG 8192

typedef __attribute__((ext_vector_type(8))) _Float16 f16x8;
typedef __attribute__((ext_vector_type(16))) float f32x16;
typedef __attribute__((ext_vector_type(4))) int i32x4;
typedef __attribute__((ext_vector_type(16))) int i32x16;

// ---------------- workspace layout ----------------
// 0       : 20 f32     mean
// 5632    : 500 f32    alpha
// 7680    : 500*20 u64 lwp
// 87808   : 512*1024 f32 partial (ends 2184960)
// 8607488 : 16*1024 f32 partial2 (ends 8673024)
// 8673024 : 25*2*64 i32x4 Bg (conv2 weight frags, 51200 B, ends 8724224)

__global__ __launch_bounds__(256) void prepsum_k(const float* __restrict__ lw,
                                                 const float* __restrict__ w2,
                                                 const float* __restrict__ x,
                                                 unsigned long long* __restrict__ lwp,
                                                 float* __restrict__ alpha,
                                                 i32x4* __restrict__ bg,
                                                 float* __restrict__ partial) {
  int b = blockIdx.x, tid = threadIdx.x;
  if (b < 125) {
    int wave = tid >> 6, lane = tid & 63;
    int j = b * 4 + wave;
    float pa = 0.f;
    for (int k = lane; k < 1250; k += 64) pa += fabsf(lw[j * 1250 + k]);
    for (int o = 32; o > 0; o >>= 1) pa += __shfl_down(pa, o, 64);
    if (lane == 0) alpha[j] = pa / 1250.0f;
    if (lane < 20) {
      unsigned long long m = 0;
      int base = j * 1250 + lane * 64;
      int lim = 1250 - lane * 64; if (lim > 64) lim = 64;
      for (int bb = 0; bb < lim; ++bb)
        if (lw[base + bb] > 0.f) m |= (1ull << bb);
      lwp[j * 20 + lane] = m;
    }
  } else if (b < 138) {
    // conv2 weight fragments in MFMA B layout:
    // Bg[(t*2+nt)*64 + l] = 16 bytes, byte j is k = 16*(l>>5)+j,
    // col oc = nt*32 + (l&31); sign(w2) for k<20 && oc<50 else 0.
    int idx = (b - 125) * 256 + tid;
    if (idx < 3200) {
      int t = idx >> 7;
      int rem = idx & 127;
      int l = rem & 63;
      int nt = rem >> 6;
      int oc = nt * 32 + (l & 31);
      int hi = l >> 5;
      i32x4 o4;
#pragma unroll
      for (int wi = 0; wi < 4; ++wi) {
        int word = 0;
#pragma unroll
        for (int bb = 0; bb < 4; ++bb) {
          int k = hi * 16 + wi * 4 + bb;
          int v = 0;
          if (k < 20 && oc < 50)
            v = (w2[(oc * 20 + k) * 25 + t] > 0.f) ? 1 : -1;
          word |= (v & 0xff) << (8 * bb);
        }
        o4[wi] = word;
      }
      bg[idx] = o4;
    }
  } else {
    int sb = b - 138;
    const float4* xv = (const float4*)x + (size_t)sb * 16 * 256;
    float ax = 0.f, ay = 0.f, az = 0.f, aw = 0.f;
    for (int nn = 0; nn < 16; ++nn) {
      float4 v = xv[nn * 256 + tid];
      ax += v.x; ay += v.y; az += v.z; aw += v.w;
    }
    float4 r; r.x = ax; r.y = ay; r.z = az; r.w = aw;
    ((float4*)(partial + (size_t)sb * 1024))[tid] = r;
  }
}

__global__ __launch_bounds__(256) void reduce_k(const float* __restrict__ partial,
                                                float* __restrict__ partial2) {
  int b = blockIdx.x, tid = threadIdx.x;
  int e = (b & 3) * 256 + tid;
  int p0 = (b >> 2) * 32;
  float s = 0.f;
#pragma unroll
  for (int p = 0; p < 32; ++p) s += partial[(size_t)(p0 + p) * 1024 + e];
  partial2[(size_t)(b >> 2) * 1024 + e] = s;
}

__global__ __launch_bounds__(256) void mean_k(const float* __restrict__ partial2,
                                              const float* __restrict__ w1,
                                              float* __restrict__ mean) {
  __shared__ float Tsh[1024];
  __shared__ double U8[25][8];
  __shared__ double U[25];
  int t = threadIdx.x;
  for (int e = t; e < 1024; e += 256) {
    double s = 0.0;
#pragma unroll
    for (int b = 0; b < 16; ++b) s += (double)partial2[b * 1024 + e];
    Tsh[e] = (float)s;
  }
  __syncthreads();
  if (t < 200) {
    int tap = t >> 3, part = t & 7;
    int ky = tap / 5, kx = tap % 5;
    double s = 0.0;
    for (int p = part * 98; p < part * 98 + 98; ++p) {
      int py = p / 28, px = p % 28;
      s += (double)Tsh[(py + ky) * 32 + px + kx];
    }
    U8[tap][part] = s;
  }
  __syncthreads();
  if (t < 25) {
    double s = 0.0;
    for (int i = 0; i < 8; ++i) s += U8[t][i];
    U[t] = s;
  }
  __syncthreads();
  if (t < 20) {
    double s = 0.0;
    for (int q = 0; q < 25; ++q) s += (double)w1[t * 25 + q] * U[q];
    mean[t] = (float)(s / (8192.0 * 784.0));
  }
}

__device__ inline uint32_t pack_f16_pair(float fv) {
  _Float16 h = (_Float16)fv;
  float rem = fv - (float)h;
  _Float16 l = (_Float16)(rem * 4096.0f);
  uint32_t hb = (uint32_t)__builtin_bit_cast(unsigned short, h);
  uint32_t lb = (uint32_t)__builtin_bit_cast(unsigned short, l);
  return (hb << 16) | lb;
}

// Fused conv1(f16 MFMA) + conv2(i8 MFMA) + lin + fc.
// Block = 512 thr = 8 waves = 8 images.
__global__ __launch_bounds__(512, 4) void conv12_k(const float* __restrict__ x,
                                                   const float* __restrict__ w1,
                                                   const float* __restrict__ mean,
                                                   const i32x4* __restrict__ bg,
                                                   const unsigned long long* __restrict__ lwp,
                                                   const float* __restrict__ alpha,
                                                   const float* __restrict__ fcw,
                                                   const float* __restrict__ fcb,
                                                   float* __restrict__ out) {
  __shared__ uint32_t xs8[8][1032];                           // 33024 B
  __shared__ uint32_t b1sh[1568];                             // 6272 B
  __shared__ __attribute__((aligned(16))) char uni[8][2048];  // 16384 B
  int tid = threadIdx.x;
  int wave = tid >> 6, lane = tid & 63;
  int n0 = blockIdx.x * 8;
  int n = n0 + wave;

  // ================= phase 1: conv1 (wave-private) =================
  uint32_t* xs = xs8[wave];
  {
    const float4* xin = (const float4*)(x + (size_t)n * 1024);
#pragma unroll
    for (int i = 0; i < 4; ++i) {
      int idx = i * 64 + lane;
      float4 v = xin[idx];
      float fv[4] = {v.x, v.y, v.z, v.w};
#pragma unroll
      for (int e = 0; e < 4; ++e)
        xs[4 * idx + e] = pack_f16_pair(fv[e]);
    }
    if (lane < 8) xs[1024 + lane] = 0;  // pad slots
  }

  // B fragments: Bh (hi), Bhs (hi*4096 exact), Bl (lo*4096)
  int bc = lane & 31;
  int khsel = lane >> 5;
  {
    f16x8 Bh[2], Bhs[2], Bl[2];
    const int t1tab[8] = {8, 9, 18, 19, 20, 21, 22, 23};
    const _Float16 SC = (_Float16)4096.0f;
#pragma unroll
    for (int j = 0; j < 8; ++j) {
      int t0 = j + khsel * 10;
      float wv0 = (bc < 20) ? w1[bc * 25 + t0] : 0.f;
      uint32_t p0 = pack_f16_pair(wv0);
      _Float16 h0 = __builtin_bit_cast(_Float16, (unsigned short)(p0 >> 16));
      Bh[0][j] = h0;
      Bhs[0][j] = h0 * SC;
      Bl[0][j] = __builtin_bit_cast(_Float16, (unsigned short)(p0 & 0xffffu));
      float wv1 = 0.f;
      if (bc < 20) {
        if (khsel == 0) wv1 = w1[bc * 25 + t1tab[j]];
        else if (j == 4) wv1 = w1[bc * 25 + 24];
      }
      uint32_t p1 = pack_f16_pair(wv1);
      _Float16 h1 = __builtin_bit_cast(_Float16, (unsigned short)(p1 >> 16));
      Bh[1][j] = h1;
      Bhs[1][j] = h1 * SC;
      Bl[1][j] = __builtin_bit_cast(_Float16, (unsigned short)(p1 & 0xffffu));
    }
    float mv = (bc < 20) ? mean[bc] * 4096.0f : 3.0e38f;

    int m = lane & 31;
    int d0 = m + khsel * 64;
    int d1 = m + khsel * 4;

    for (int pp = 0; pp < 14; ++pp) {
      unsigned long long bacc[16];
#pragma unroll
      for (int r = 0; r < 16; ++r) bacc[r] = 0ull;
#pragma unroll
      for (int py2 = 0; py2 < 2; ++py2) {
        int pybase = (2 * pp + py2) * 32;
        const uint32_t* b0 = xs + pybase + d0;
        const uint32_t* b1 = xs + pybase + d1;
        uint32_t raw[16];
        raw[0] = b0[0];   raw[1] = b0[1];   raw[2] = b0[2];   raw[3] = b0[3];
        raw[4] = b0[4];   raw[5] = b0[32];  raw[6] = b0[33];  raw[7] = b0[34];
        raw[8] = b1[35];  raw[9] = b1[36];  raw[10] = b1[99]; raw[11] = b1[100];
        raw[12] = b1[128]; raw[13] = b1[129]; raw[14] = b1[130]; raw[15] = b1[131];
        f16x8 Ah[2], Al[2];
#pragma unroll
        for (int kh = 0; kh < 2; ++kh) {
          uint32_t hw[4], lw2[4];
#pragma unroll
          for (int jj = 0; jj < 4; ++jj) {
            uint32_t v0 = raw[kh * 8 + 2 * jj], v1 = raw[kh * 8 + 2 * jj + 1];
            hw[jj] = __builtin_amdgcn_perm(v1, v0, 0x07060302u);
            lw2[jj] = __builtin_amdgcn_perm(v1, v0, 0x05040100u);
          }
          struct U4 { uint32_t a, b, c, d; };
          U4 hv4 = {hw[0], hw[1], hw[2], hw[3]};
          U4 lv4 = {lw2[0], lw2[1], lw2[2], lw2[3]};
          Ah[kh] = __builtin_bit_cast(f16x8, hv4);
          Al[kh] = __builtin_bit_cast(f16x8, lv4);
        }
        f32x16 acc;
#pragma unroll
        for (int i = 0; i < 16; ++i) acc[i] = 0.f;
        acc = __builtin_amdgcn_mfma_f32_32x32x16_f16(Ah[0], Bhs[0], acc, 0, 0, 0);
        acc = __builtin_amdgcn_mfma_f32_32x32x16_f16(Ah[1], Bhs[1], acc, 0, 0, 0);
        acc = __builtin_amdgcn_mfma_f32_32x32x16_f16(Ah[0], Bl[0], acc, 0, 0, 0);
        acc = __builtin_amdgcn_mfma_f32_32x32x16_f16(Ah[1], Bl[1], acc, 0, 0, 0);
        acc = __builtin_amdgcn_mfma_f32_32x32x16_f16(Al[0], Bh[0], acc, 0, 0, 0);
        acc = __builtin_amdgcn_mfma_f32_32x32x16_f16(Al[1], Bh[1], acc, 0, 0, 0);
        // C/D: channel = lane&31, px = (r&3) + 8*(r>>2) + 4*(lane>>5)
#pragma unroll
        for (int r = 0; r < 16; ++r)
          bacc[r] |= __ballot(acc[r] > mv);
      }
      uint32_t pm = 0;
#pragma unroll
      for (int pc = 0; pc < 14; ++pc) {
        int px0 = 2 * pc;
        int r0 = (px0 & 3) + 4 * (px0 >> 3);
        int h0 = (px0 >> 2) & 1;
        unsigned long long mm = bacc[r0] | bacc[r0 + 1];
        uint32_t val = (uint32_t)(mm >> (32 * h0));
        if (lane == pc) pm = val;
      }
      if (lane < 14) b1sh[wave * 196 + pp * 14 + lane] = pm;
    }
  }
  __syncthreads();

  // ================= phase 2: conv2 (i8 MFMA, reg-built A) =================
  // M = 8img*25quads*4 = 25 tiles; A spread from b1sh bits (20..31 are 0).
  {
    int m = lane & 31, hi = lane >> 5;
    int shbase = hi * 16;
    for (int mt = wave; mt < 25; mt += 8) {
      int qg = mt * 8 + (m >> 2);
      int img = (qg * 41) >> 10;       // /25 for qg<200
      int quad = qg - img * 25;
      int Y = (quad * 13) >> 6;        // /5 for quad<25
      int X = quad - Y * 5;
      int px = (2 * Y + ((m >> 1) & 1)) * 14 + 2 * X + (m & 1);
      const uint32_t* arow = b1sh + img * 196 + px;
      const i32x4* bgl = bg + lane;
      i32x16 acc0, acc1;
#pragma unroll
      for (int i = 0; i < 16; ++i) { acc0[i] = 0; acc1[i] = 0; }
#pragma unroll 1
      for (int ky = 0; ky < 5; ++ky) {
        const uint32_t* ar2 = arow + ky * 14;
        const i32x4* bg2 = bgl + ky * 5 * 128;
#pragma unroll
        for (int kx = 0; kx < 5; ++kx) {
          uint32_t w = ar2[kx];
          i32x4 av;
#pragma unroll
          for (int wi = 0; wi < 4; ++wi)
            av[wi] = (int)((((w >> (shbase + 4 * wi)) & 0xFu) * 0x00204081u) & 0x01010101u);
          i32x4 bv0 = bg2[kx * 128];
          i32x4 bv1 = bg2[kx * 128 + 64];
          acc0 = __builtin_amdgcn_mfma_i32_32x32x32_i8(av, bv0, acc0, 0, 0, 0);
          acc1 = __builtin_amdgcn_mfma_i32_32x32x32_i8(av, bv1, acc1, 0, 0, 0);
        }
      }
      // readout: col oc = nt*32 + (lane&31); rows 4*(2g+hi)+{0..3} = regs 4g..4g+3
      int oc0 = m, oc1 = 32 + m;
#pragma unroll
      for (int g = 0; g < 4; ++g) {
        int qloc = 2 * g + hi;
        int qg2 = mt * 8 + qloc;
        int img2 = (qg2 * 41) >> 10;
        int quad2 = qg2 - img2 * 25;
        {
          int a0 = acc0[4 * g], a1 = acc0[4 * g + 1], a2 = acc0[4 * g + 2], a3 = acc0[4 * g + 3];
          int c0 = a0 > a1 ? a0 : a1, c1 = a2 > a3 ? a2 : a3;
          int best = c0 > c1 ? c0 : c1;
          uni[img2][oc0 * 25 + quad2] = (char)((best > 0) - (best < 0));
        }
        if (oc1 < 50) {
          int a0 = acc1[4 * g], a1 = acc1[4 * g + 1], a2 = acc1[4 * g + 2], a3 = acc1[4 * g + 3];
          int c0 = a0 > a1 ? a0 : a1, c1 = a2 > a3 ? a2 : a3;
          int best = c0 > c1 ? c0 : c1;
          uni[img2][oc1 * 25 + quad2] = (char)((best > 0) - (best < 0));
        }
      }
    }
  }
  __syncthreads();

  // ================= phase 3: linear + fc (per-wave own image) =============
  signed char* s2w = (signed char*)uni[wave];
  float* hshw = (float*)uni[wave];
  if (lane < 30) s2w[1250 + lane] = 0;

  unsigned long long Pm[20], Nm[20];
  int cp = 0, cn = 0;
#pragma unroll
  for (int k = 0; k < 20; ++k) {
    signed char v = s2w[k * 64 + lane];
    unsigned long long P = __ballot(v > 0);
    unsigned long long N = __ballot(v < 0);
    Pm[k] = P; Nm[k] = N;
    cp += __popcll(P); cn += __popcll(N);
  }

#pragma unroll
  for (int rd = 0; rd < 8; ++rd) {
    int j = rd * 64 + lane;
    float y = 0.f;
    if (j < 500) {
      const ulonglong2* W2 = (const ulonglong2*)(lwp + (size_t)j * 20);
      int a = 0, b = 0;
#pragma unroll
      for (int i = 0; i < 10; ++i) {
        ulonglong2 w2v = W2[i];
        a += __popcll(w2v.x & Pm[2 * i]) + __popcll(w2v.y & Pm[2 * i + 1]);
        b += __popcll(w2v.x & Nm[2 * i]) + __popcll(w2v.y & Nm[2 * i + 1]);
      }
      int dot = 2 * (a - b) - cp + cn;
      y = alpha[j] * (float)dot;
      y = fminf(1.0f, fmaxf(-1.0f, y));
    }
    hshw[rd * 64 + lane] = y;
  }

  float hv[8];
#pragma unroll
  for (int k = 0; k < 8; ++k) hv[k] = hshw[k * 64 + lane];
#pragma unroll
  for (int o = 0; o < 10; ++o) {
    float pa = 0.f;
#pragma unroll
    for (int k = 0; k < 8; ++k) {
      int j = k * 64 + lane;
      if (j < 500) pa += hv[k] * fcw[o * 500 + j];
    }
    for (int off = 32; off > 0; off >>= 1) pa += __shfl_down(pa, off, 64);
    if (lane == 0) out[(size_t)n * 10 + o] = pa + fcb[o];
  }
}

extern "C" void kernel_launch(void* const* d_in, const int* in_sizes, int n_in,
                              void* d_out, int out_size, void* d_ws, size_t ws_size,
                              hipStream_t stream) {
  const float* x   = (const float*)d_in[0];
  const float* w1  = (const float*)d_in[1];
  const float* w2  = (const float*)d_in[2];
  const float* lw  = (const float*)d_in[3];
  const float* fcw = (const float*)d_in[4];
  const float* fcb = (const float*)d_in[5];
  float* out = (float*)d_out;
  char* ws = (char*)d_ws;

  float*    mean  = (float*)(ws + 0);
  float*    alpha = (float*)(ws + 5632);
  unsigned long long* lwp = (unsigned long long*)(ws + 7680);
  float*    partial = (float*)(ws + 87808);
  float*    partial2 = (float*)(ws + 8607488);
  i32x4*    bg    = (i32x4*)(ws + 8673024);

  prepsum_k<<<650, 256, 0, stream>>>(lw, w2, x, lwp, alpha, bg, partial);
  reduce_k<<<64, 256, 0, stream>>>(partial, partial2);
  mean_k<<<1, 256, 0, stream>>>(partial2, w1, mean);
  conv12_k<<<1024, 512, 0, stream>>>(x, w1, mean, bg, lwp, alpha, fcw, fcb, out);
}